// Round 1
// baseline (196.679 us; speedup 1.0000x reference)
//
#include <hip/hip_runtime.h>
#include <cstdint>
#include <cstddef>

#define DEV __device__ __forceinline__

typedef __bf16 bf16x8 __attribute__((ext_vector_type(8)));
typedef float f32x4 __attribute__((ext_vector_type(4)));
typedef unsigned short us8 __attribute__((ext_vector_type(8)));
typedef unsigned short us4 __attribute__((ext_vector_type(4)));

typedef const __attribute__((address_space(1))) unsigned int GUI;
typedef __attribute__((address_space(3))) unsigned int LUI;

DEV unsigned short f2bf(float f) {
  unsigned int u = __builtin_bit_cast(unsigned int, f);
  u += 0x7fffu + ((u >> 16) & 1u);
  return (unsigned short)(u >> 16);
}
DEV float bf2f(unsigned short h) {
  unsigned int u = ((unsigned int)h) << 16;
  return __builtin_bit_cast(float, u);
}

// ---------------- convert f32 -> bf16 (vectorized) ----------------
__global__ void k_f32_to_bf16(const float* __restrict__ in, unsigned short* __restrict__ out, int n4) {
  int i = blockIdx.x * blockDim.x + threadIdx.x;
  if (i >= n4) return;
  float4 v = ((const float4*)in)[i];
  us4 o;
  o.x = f2bf(v.x); o.y = f2bf(v.y); o.z = f2bf(v.z); o.w = f2bf(v.w);
  *(us4*)(out + (size_t)i * 4) = o;
}

// ------------- transpose [K,N] f32 -> [N,K] bf16 ------------------
__global__ void k_transpose_bf16(const float* __restrict__ in, unsigned short* __restrict__ out,
                                 int K, int N) {
  __shared__ float tile[32][33];
  int n0 = blockIdx.x * 32, k0 = blockIdx.y * 32;
  int tx = threadIdx.x, ty = threadIdx.y;  // block (32,8)
#pragma unroll
  for (int i = 0; i < 32; i += 8)
    tile[ty + i][tx] = in[(size_t)(k0 + ty + i) * N + n0 + tx];
  __syncthreads();
#pragma unroll
  for (int i = 0; i < 32; i += 8)
    out[(size_t)(n0 + ty + i) * K + k0 + tx] = f2bf(tile[tx][ty + i]);
}

// ---------------- concat q/k/v biases -----------------------------
__global__ void k_concat_bias(const float* __restrict__ bq, const float* __restrict__ bk,
                              const float* __restrict__ bv, float* __restrict__ out) {
  int i = blockIdx.x * blockDim.x + threadIdx.x;  // 1536
  float v = (i < 512) ? bq[i] : (i < 1024 ? bk[i - 512] : bv[i - 1024]);
  out[i] = v;
}

// ---------------- bf16 MFMA GEMM: C = A @ BT^T + bias -------------
// A: [M,K] bf16 row-major, BT: [N,K] bf16 row-major (i.e. B transposed)
// MODE 0: bf16 out + bias; MODE 1: f32 out + bias; MODE 2: bf16 out + bias + exact GELU
template <int MODE>
__global__ void k_gemm(const unsigned short* __restrict__ A,
                       const unsigned short* __restrict__ BT,
                       const float* __restrict__ bias,
                       void* __restrict__ outp, int K, int N) {
  __shared__ __align__(16) unsigned short As[128 * 32];
  __shared__ __align__(16) unsigned short Bs[128 * 32];
  const int tid = threadIdx.x;
  const int wave = tid >> 6, lane = tid & 63;
  const int wm = wave >> 1, wn = wave & 1;
  const int rbase = blockIdx.y * 128;
  const int nbase = blockIdx.x * 128;

  f32x4 acc[4][4] = {};

  const int nkt = K >> 5;
  for (int kt = 0; kt < nkt; ++kt) {
    const int k0 = kt << 5;
    // stage A,B tiles: 128x32 bf16 each = 8KB; per wave 2x(64 lanes x 16B) per tile
#pragma unroll
    for (int t = 0; t < 2; ++t) {
      int cidx = (wave + t * 4) * 64 + lane;  // 16B-chunk index [0,512)
      int row = cidx >> 2;
      int col = (cidx & 3) << 3;
      const unsigned short* ga = A + (size_t)(rbase + row) * K + k0 + col;
      const unsigned short* gb = BT + (size_t)(nbase + row) * K + k0 + col;
      __builtin_amdgcn_global_load_lds((GUI*)ga, (LUI*)(As + (wave + t * 4) * 512), 16, 0, 0);
      __builtin_amdgcn_global_load_lds((GUI*)gb, (LUI*)(Bs + (wave + t * 4) * 512), 16, 0, 0);
    }
    __syncthreads();

    bf16x8 af[4], bfr[4];
#pragma unroll
    for (int m = 0; m < 4; ++m) {
      int row = wm * 64 + m * 16 + (lane & 15);
      af[m] = __builtin_bit_cast(bf16x8, *(const us8*)(As + row * 32 + ((lane >> 4) << 3)));
    }
#pragma unroll
    for (int n = 0; n < 4; ++n) {
      int row = wn * 64 + n * 16 + (lane & 15);
      bfr[n] = __builtin_bit_cast(bf16x8, *(const us8*)(Bs + row * 32 + ((lane >> 4) << 3)));
    }
#pragma unroll
    for (int m = 0; m < 4; ++m)
#pragma unroll
      for (int n = 0; n < 4; ++n)
        acc[m][n] = __builtin_amdgcn_mfma_f32_16x16x32_bf16(af[m], bfr[n], acc[m][n], 0, 0, 0);
    __syncthreads();
  }

#pragma unroll
  for (int m = 0; m < 4; ++m) {
    int grow0 = rbase + wm * 64 + m * 16 + ((lane >> 4) << 2);
#pragma unroll
    for (int n = 0; n < 4; ++n) {
      int gcol = nbase + wn * 64 + n * 16 + (lane & 15);
      float bv_ = bias[gcol];
#pragma unroll
      for (int r = 0; r < 4; ++r) {
        int grow = grow0 + r;
        float v = acc[m][n][r] + bv_;
        if (MODE == 2) v = 0.5f * v * (1.0f + erff(v * 0.70710678118654752f));
        if (MODE == 1)
          ((float*)outp)[(size_t)grow * N + gcol] = v;
        else
          ((unsigned short*)outp)[(size_t)grow * N + gcol] = f2bf(v);
      }
    }
  }
}

// ---------------- windowed causal attention -----------------------
// qkv: [8192, 1536] bf16 (cols 0-511 q, 512-1023 k, 1024-1535 v, col = h*64+dh)
// out: [8192, 512] bf16
__global__ __launch_bounds__(256) void k_attn(const unsigned short* __restrict__ qkv,
                                              unsigned short* __restrict__ attnb) {
  const int wave = threadIdx.x >> 6, lane = threadIdx.x & 63;
  const int gq = blockIdx.x * 4 + wave;  // [0, 65536)
  const int i = gq & 2047;
  const int bh = gq >> 11;
  const int h = bh & 7, b = bh >> 3;
  const size_t row = (size_t)(b * 2048 + i);
  const int ld = 1536;
  const int hc = h * 64 + lane;

  float qd = bf2f(qkv[row * ld + hc]);

  float s[10];
#pragma unroll
  for (int jj = 0; jj < 10; ++jj) {
    int j = i - 9 + jj;
    bool ok = (j >= 0);
    int jc = ok ? j : 0;
    float kd = bf2f(qkv[(size_t)(b * 2048 + jc) * ld + 512 + hc]);
    float p = qd * kd;
#pragma unroll
    for (int m = 32; m >= 1; m >>= 1) p += __shfl_xor(p, m);
    s[jj] = ok ? p * 0.125f : -1e30f;
  }
  float mx = s[9];
#pragma unroll
  for (int jj = 0; jj < 9; ++jj) mx = fmaxf(mx, s[jj]);
  float den = 0.f;
#pragma unroll
  for (int jj = 0; jj < 10; ++jj) {
    float e = __expf(s[jj] - mx);
    s[jj] = e;
    den += e;
  }
  float inv = 1.f / den;
  float o = 0.f;
#pragma unroll
  for (int jj = 0; jj < 10; ++jj) {
    int j = i - 9 + jj;
    int jc = (j >= 0) ? j : 0;
    float vd = bf2f(qkv[(size_t)(b * 2048 + jc) * ld + 1024 + hc]);
    o += s[jj] * vd;
  }
  attnb[row * 512 + hc] = f2bf(o * inv);
}

// ---------------- residual + LayerNorm ----------------------------
// y = LN(res + add); writes f32 (and optionally bf16 copy)
__global__ __launch_bounds__(256) void k_ln(const float* __restrict__ res,
                                            const float* __restrict__ add,
                                            const float* __restrict__ w,
                                            const float* __restrict__ bb,
                                            float* __restrict__ out_f32,
                                            unsigned short* __restrict__ out_bf16) {
  const int wave = threadIdx.x >> 6, lane = threadIdx.x & 63;
  const int row = blockIdx.x * 4 + wave;
  const float4* r4 = (const float4*)(res + (size_t)row * 512);
  const float4* a4 = (const float4*)(add + (size_t)row * 512);
  float4 x[2];
  float sum = 0.f, ss = 0.f;
#pragma unroll
  for (int t = 0; t < 2; ++t) {
    float4 rv = r4[lane * 2 + t], av = a4[lane * 2 + t];
    float4 y;
    y.x = rv.x + av.x; y.y = rv.y + av.y; y.z = rv.z + av.z; y.w = rv.w + av.w;
    x[t] = y;
    sum += y.x + y.y + y.z + y.w;
    ss += y.x * y.x + y.y * y.y + y.z * y.z + y.w * y.w;
  }
#pragma unroll
  for (int m = 32; m >= 1; m >>= 1) {
    sum += __shfl_xor(sum, m);
    ss += __shfl_xor(ss, m);
  }
  const float mu = sum * (1.f / 512.f);
  float var = ss * (1.f / 512.f) - mu * mu;
  const float rstd = rsqrtf(var + 1e-5f);
#pragma unroll
  for (int t = 0; t < 2; ++t) {
    int c = lane * 8 + t * 4;
    float4 wv = *(const float4*)(w + c);
    float4 bv = *(const float4*)(bb + c);
    float4 y = x[t];
    float4 o;
    o.x = (y.x - mu) * rstd * wv.x + bv.x;
    o.y = (y.y - mu) * rstd * wv.y + bv.y;
    o.z = (y.z - mu) * rstd * wv.z + bv.z;
    o.w = (y.w - mu) * rstd * wv.w + bv.w;
    if (out_f32) *(float4*)(out_f32 + (size_t)row * 512 + c) = o;
    if (out_bf16) {
      us4 u;
      u.x = f2bf(o.x); u.y = f2bf(o.y); u.z = f2bf(o.z); u.w = f2bf(o.w);
      *(us4*)(out_bf16 + (size_t)row * 512 + c) = u;
    }
  }
}

extern "C" void kernel_launch(void* const* d_in, const int* in_sizes, int n_in,
                              void* d_out, int out_size, void* d_ws, size_t ws_size,
                              hipStream_t stream) {
  const float* z    = (const float*)d_in[0];
  const float* Wq   = (const float*)d_in[1];
  const float* bq   = (const float*)d_in[2];
  const float* Wk   = (const float*)d_in[3];
  const float* bk   = (const float*)d_in[4];
  const float* Wv   = (const float*)d_in[5];
  const float* bv   = (const float*)d_in[6];
  const float* Wo   = (const float*)d_in[7];
  const float* bo   = (const float*)d_in[8];
  const float* ln1w = (const float*)d_in[9];
  const float* ln1b = (const float*)d_in[10];
  const float* W1   = (const float*)d_in[11];
  const float* b1   = (const float*)d_in[12];
  const float* W2   = (const float*)d_in[13];
  const float* b2   = (const float*)d_in[14];
  const float* ln2w = (const float*)d_in[15];
  const float* ln2b = (const float*)d_in[16];
  float* out = (float*)d_out;

  char* ws = (char*)d_ws;
  size_t off = 0;
  auto alloc = [&](size_t bytes) {
    char* p = ws + off;
    off += (bytes + 255) & ~(size_t)255;
    return p;
  };
  unsigned short* WTqkv = (unsigned short*)alloc(1536 * 512 * 2);
  unsigned short* WoT   = (unsigned short*)alloc(512 * 512 * 2);
  unsigned short* W1T   = (unsigned short*)alloc(2048 * 512 * 2);
  unsigned short* W2T   = (unsigned short*)alloc(512 * 2048 * 2);
  float*          biasqkv = (float*)alloc(1536 * 4);
  unsigned short* zb    = (unsigned short*)alloc((size_t)8192 * 512 * 2);
  unsigned short* qkvb  = (unsigned short*)alloc((size_t)8192 * 1536 * 2);
  unsigned short* attnb = (unsigned short*)alloc((size_t)8192 * 512 * 2);
  float*          proj  = (float*)alloc((size_t)8192 * 512 * 4);
  float*          z1    = (float*)alloc((size_t)8192 * 512 * 4);
  unsigned short* z1b   = zb;    // reuse (zb dead after QKV GEMM)
  unsigned short* ff    = qkvb;  // reuse qkvb+attnb (contiguous 33.5MB; dead after Wo GEMM)

  dim3 tb(32, 8);
  k_f32_to_bf16<<<4096, 256, 0, stream>>>(z, zb, 1048576);
  k_transpose_bf16<<<dim3(16, 16), tb, 0, stream>>>(Wq, WTqkv, 512, 512);
  k_transpose_bf16<<<dim3(16, 16), tb, 0, stream>>>(Wk, WTqkv + 512 * 512, 512, 512);
  k_transpose_bf16<<<dim3(16, 16), tb, 0, stream>>>(Wv, WTqkv + 1024 * 512, 512, 512);
  k_transpose_bf16<<<dim3(16, 16), tb, 0, stream>>>(Wo, WoT, 512, 512);
  k_transpose_bf16<<<dim3(64, 16), tb, 0, stream>>>(W1, W1T, 512, 2048);
  k_transpose_bf16<<<dim3(16, 64), tb, 0, stream>>>(W2, W2T, 2048, 512);
  k_concat_bias<<<6, 256, 0, stream>>>(bq, bk, bv, biasqkv);

  // QKV: [8192,512] @ [512,1536] -> qkvb
  k_gemm<0><<<dim3(12, 64), 256, 0, stream>>>(zb, WTqkv, biasqkv, qkvb, 512, 1536);
  // windowed attention
  k_attn<<<16384, 256, 0, stream>>>(qkvb, attnb);
  // Wo proj: [8192,512] @ [512,512] -> proj (f32)
  k_gemm<1><<<dim3(4, 64), 256, 0, stream>>>(attnb, WoT, bo, proj, 512, 512);
  // z1 = LN(z + proj)
  k_ln<<<2048, 256, 0, stream>>>(z, proj, ln1w, ln1b, z1, z1b);
  // FFN1: [8192,512] @ [512,2048] + GELU -> ff (bf16)
  k_gemm<2><<<dim3(16, 64), 256, 0, stream>>>(z1b, W1T, b1, ff, 512, 2048);
  // FFN2: [8192,2048] @ [2048,512] -> proj (f32)
  k_gemm<1><<<dim3(4, 64), 256, 0, stream>>>(ff, W2T, b2, proj, 2048, 512);
  // out = LN(z1 + proj)
  k_ln<<<2048, 256, 0, stream>>>(z1, proj, ln2w, ln2b, out, nullptr);
}

// Round 2
// 173.608 us; speedup vs baseline: 1.1329x; 1.1329x over previous
//
#include <hip/hip_runtime.h>
#include <cstdint>
#include <cstddef>

#define DEV __device__ __forceinline__

typedef __bf16 bf16x8 __attribute__((ext_vector_type(8)));
typedef float f32x4 __attribute__((ext_vector_type(4)));
typedef unsigned short us8 __attribute__((ext_vector_type(8)));
typedef unsigned short us4 __attribute__((ext_vector_type(4)));

typedef const __attribute__((address_space(1))) unsigned int GUI;
typedef __attribute__((address_space(3))) unsigned int LUI;

DEV unsigned short f2bf(float f) {
  unsigned int u = __builtin_bit_cast(unsigned int, f);
  u += 0x7fffu + ((u >> 16) & 1u);
  return (unsigned short)(u >> 16);
}
DEV float bf2f(unsigned short h) {
  unsigned int u = ((unsigned int)h) << 16;
  return __builtin_bit_cast(float, u);
}

// ---------------- convert f32 -> bf16 (vectorized) ----------------
__global__ void k_f32_to_bf16(const float* __restrict__ in, unsigned short* __restrict__ out, int n4) {
  int i = blockIdx.x * blockDim.x + threadIdx.x;
  if (i >= n4) return;
  float4 v = ((const float4*)in)[i];
  us4 o;
  o.x = f2bf(v.x); o.y = f2bf(v.y); o.z = f2bf(v.z); o.w = f2bf(v.w);
  *(us4*)(out + (size_t)i * 4) = o;
}

// ------------- transpose [K,N] f32 -> [N,K] bf16 ------------------
__global__ void k_transpose_bf16(const float* __restrict__ in, unsigned short* __restrict__ out,
                                 int K, int N) {
  __shared__ float tile[32][33];
  int n0 = blockIdx.x * 32, k0 = blockIdx.y * 32;
  int tx = threadIdx.x, ty = threadIdx.y;  // block (32,8)
#pragma unroll
  for (int i = 0; i < 32; i += 8)
    tile[ty + i][tx] = in[(size_t)(k0 + ty + i) * N + n0 + tx];
  __syncthreads();
#pragma unroll
  for (int i = 0; i < 32; i += 8)
    out[(size_t)(n0 + ty + i) * K + k0 + tx] = f2bf(tile[tx][ty + i]);
}

// ---------------- concat q/k/v biases -----------------------------
__global__ void k_concat_bias(const float* __restrict__ bq, const float* __restrict__ bk,
                              const float* __restrict__ bv, float* __restrict__ out) {
  int i = blockIdx.x * blockDim.x + threadIdx.x;  // 1536
  float v = (i < 512) ? bq[i] : (i < 1024 ? bk[i - 512] : bv[i - 1024]);
  out[i] = v;
}

// ---------------- bf16 MFMA GEMM: C = A @ BT^T + bias -------------
// A: [M,K] bf16 row-major, BT: [N,K] bf16 row-major (i.e. B transposed)
// MODE 0: bf16 out + bias; MODE 1: f32 out + bias; MODE 2: bf16 out + bias + exact GELU
template <int MODE>
__global__ void k_gemm(const unsigned short* __restrict__ A,
                       const unsigned short* __restrict__ BT,
                       const float* __restrict__ bias,
                       void* __restrict__ outp, int K, int N) {
  __shared__ __align__(16) unsigned short As[128 * 32];
  __shared__ __align__(16) unsigned short Bs[128 * 32];
  const int tid = threadIdx.x;
  const int wave = tid >> 6, lane = tid & 63;
  const int wm = wave >> 1, wn = wave & 1;
  const int rbase = blockIdx.y * 128;
  const int nbase = blockIdx.x * 128;

  f32x4 acc[4][4] = {};

  const int nkt = K >> 5;
  for (int kt = 0; kt < nkt; ++kt) {
    const int k0 = kt << 5;
#pragma unroll
    for (int t = 0; t < 2; ++t) {
      int cidx = (wave + t * 4) * 64 + lane;  // 16B-chunk index [0,512)
      int row = cidx >> 2;
      int col = (cidx & 3) << 3;
      const unsigned short* ga = A + (size_t)(rbase + row) * K + k0 + col;
      const unsigned short* gb = BT + (size_t)(nbase + row) * K + k0 + col;
      __builtin_amdgcn_global_load_lds((GUI*)ga, (LUI*)(As + (wave + t * 4) * 512), 16, 0, 0);
      __builtin_amdgcn_global_load_lds((GUI*)gb, (LUI*)(Bs + (wave + t * 4) * 512), 16, 0, 0);
    }
    __syncthreads();

    bf16x8 af[4], bfr[4];
#pragma unroll
    for (int m = 0; m < 4; ++m) {
      int row = wm * 64 + m * 16 + (lane & 15);
      af[m] = __builtin_bit_cast(bf16x8, *(const us8*)(As + row * 32 + ((lane >> 4) << 3)));
    }
#pragma unroll
    for (int n = 0; n < 4; ++n) {
      int row = wn * 64 + n * 16 + (lane & 15);
      bfr[n] = __builtin_bit_cast(bf16x8, *(const us8*)(Bs + row * 32 + ((lane >> 4) << 3)));
    }
#pragma unroll
    for (int m = 0; m < 4; ++m)
#pragma unroll
      for (int n = 0; n < 4; ++n)
        acc[m][n] = __builtin_amdgcn_mfma_f32_16x16x32_bf16(af[m], bfr[n], acc[m][n], 0, 0, 0);
    __syncthreads();
  }

#pragma unroll
  for (int m = 0; m < 4; ++m) {
    int grow0 = rbase + wm * 64 + m * 16 + ((lane >> 4) << 2);
#pragma unroll
    for (int n = 0; n < 4; ++n) {
      int gcol = nbase + wn * 64 + n * 16 + (lane & 15);
      float bv_ = bias[gcol];
#pragma unroll
      for (int r = 0; r < 4; ++r) {
        int grow = grow0 + r;
        float v = acc[m][n][r] + bv_;
        if (MODE == 2) v = 0.5f * v * (1.0f + erff(v * 0.70710678118654752f));
        if (MODE == 1)
          ((float*)outp)[(size_t)grow * N + gcol] = v;
        else
          ((unsigned short*)outp)[(size_t)grow * N + gcol] = f2bf(v);
      }
    }
  }
}

// ---------------- windowed causal attention (v2) ------------------
// One wave (64 threads) per block; block handles 64 queries of one (b,h).
// Phase 1: stage Q^T, K^T into LDS (f32).  Phase 2: lane=query computes
// 10 window scores via plain FMA chains (no cross-lane ops), softmax in
// registers, normalized probs -> LDS P.  Phase 3: lane=d, 4 queries per
// iter sharing 13 overlapping V loads (global, L1-resident), coalesced
// bf16 stores.
__global__ __launch_bounds__(64) void k_attn(const unsigned short* __restrict__ qkv,
                                             unsigned short* __restrict__ attnb) {
  __shared__ float Qt[64 * 67];  // [d][q], stride 67
  __shared__ float Kt[64 * 75];  // [d][t], t = j - (i0-9), stride 75
  __shared__ float P[64 * 12];   // [q][jj], stride 12 (16B-aligned rows)

  const int lane = threadIdx.x;
  const int bid = blockIdx.x;          // 1024 = 32 chunks x 32 bh
  const int chunk = bid & 31;
  const int bh = bid >> 5;
  const int h = bh & 7, b = bh >> 3;
  const int i0 = chunk * 64;
  const int b2048 = b * 2048;
  const int h64 = h * 64;

  // ---- stage K^T (73 rows) and Q^T (64 rows); lane = d ----
#pragma unroll 8
  for (int r = 0; r < 73; ++r) {
    int jloc = i0 - 9 + r;
    int jc = jloc < 0 ? 0 : jloc;
    Kt[lane * 75 + r] = bf2f(qkv[(size_t)(b2048 + jc) * 1536 + 512 + h64 + lane]);
  }
#pragma unroll 8
  for (int r = 0; r < 64; ++r) {
    Qt[lane * 67 + r] = bf2f(qkv[(size_t)(b2048 + i0 + r) * 1536 + h64 + lane]);
  }
  __syncthreads();

  // ---- scores: lane = query (i = i0 + lane) ----
  float s[10];
#pragma unroll
  for (int jj = 0; jj < 10; ++jj) s[jj] = 0.f;
#pragma unroll
  for (int d = 0; d < 64; ++d) {
    float qd = Qt[d * 67 + lane];
#pragma unroll
    for (int jj = 0; jj < 10; ++jj)
      s[jj] = fmaf(qd, Kt[d * 75 + lane + jj], s[jj]);
  }
  const int iG = i0 + lane;
#pragma unroll
  for (int jj = 0; jj < 10; ++jj)
    s[jj] = (iG - 9 + jj >= 0) ? s[jj] * 0.125f : -1e30f;
  float mx = s[9];
#pragma unroll
  for (int jj = 0; jj < 9; ++jj) mx = fmaxf(mx, s[jj]);
  float den = 0.f;
#pragma unroll
  for (int jj = 0; jj < 10; ++jj) {
    s[jj] = __expf(s[jj] - mx);
    den += s[jj];
  }
  float inv = 1.f / den;
#pragma unroll
  for (int jj = 0; jj < 10; ++jj) P[lane * 12 + jj] = s[jj] * inv;
  __syncthreads();

  // ---- PV: lane = d; 4 queries per iter share 13 V loads ----
  for (int q0 = 0; q0 < 64; q0 += 4) {
    float vv[13];
#pragma unroll
    for (int t = 0; t < 13; ++t) {
      int jloc = i0 + q0 - 9 + t;
      int jc = jloc < 0 ? 0 : jloc;
      vv[t] = bf2f(qkv[(size_t)(b2048 + jc) * 1536 + 1024 + h64 + lane]);
    }
#pragma unroll
    for (int qq = 0; qq < 4; ++qq) {
      const int q = q0 + qq;
      const float* pp = &P[q * 12];
      float o = 0.f;
#pragma unroll
      for (int jj = 0; jj < 10; ++jj) o = fmaf(pp[jj], vv[qq + jj], o);
      attnb[(size_t)(b2048 + i0 + q) * 512 + h64 + lane] = f2bf(o);
    }
  }
}

// ---------------- residual + LayerNorm ----------------------------
// y = LN(res + add); writes f32 (and optionally bf16 copy)
__global__ __launch_bounds__(256) void k_ln(const float* __restrict__ res,
                                            const float* __restrict__ add,
                                            const float* __restrict__ w,
                                            const float* __restrict__ bb,
                                            float* __restrict__ out_f32,
                                            unsigned short* __restrict__ out_bf16) {
  const int wave = threadIdx.x >> 6, lane = threadIdx.x & 63;
  const int row = blockIdx.x * 4 + wave;
  const float4* r4 = (const float4*)(res + (size_t)row * 512);
  const float4* a4 = (const float4*)(add + (size_t)row * 512);
  float4 x[2];
  float sum = 0.f, ss = 0.f;
#pragma unroll
  for (int t = 0; t < 2; ++t) {
    float4 rv = r4[lane * 2 + t], av = a4[lane * 2 + t];
    float4 y;
    y.x = rv.x + av.x; y.y = rv.y + av.y; y.z = rv.z + av.z; y.w = rv.w + av.w;
    x[t] = y;
    sum += y.x + y.y + y.z + y.w;
    ss += y.x * y.x + y.y * y.y + y.z * y.z + y.w * y.w;
  }
#pragma unroll
  for (int m = 32; m >= 1; m >>= 1) {
    sum += __shfl_xor(sum, m);
    ss += __shfl_xor(ss, m);
  }
  const float mu = sum * (1.f / 512.f);
  float var = ss * (1.f / 512.f) - mu * mu;
  const float rstd = rsqrtf(var + 1e-5f);
#pragma unroll
  for (int t = 0; t < 2; ++t) {
    int c = lane * 8 + t * 4;
    float4 wv = *(const float4*)(w + c);
    float4 bv = *(const float4*)(bb + c);
    float4 y = x[t];
    float4 o;
    o.x = (y.x - mu) * rstd * wv.x + bv.x;
    o.y = (y.y - mu) * rstd * wv.y + bv.y;
    o.z = (y.z - mu) * rstd * wv.z + bv.z;
    o.w = (y.w - mu) * rstd * wv.w + bv.w;
    if (out_f32) *(float4*)(out_f32 + (size_t)row * 512 + c) = o;
    if (out_bf16) {
      us4 u;
      u.x = f2bf(o.x); u.y = f2bf(o.y); u.z = f2bf(o.z); u.w = f2bf(o.w);
      *(us4*)(out_bf16 + (size_t)row * 512 + c) = u;
    }
  }
}

extern "C" void kernel_launch(void* const* d_in, const int* in_sizes, int n_in,
                              void* d_out, int out_size, void* d_ws, size_t ws_size,
                              hipStream_t stream) {
  const float* z    = (const float*)d_in[0];
  const float* Wq   = (const float*)d_in[1];
  const float* bq   = (const float*)d_in[2];
  const float* Wk   = (const float*)d_in[3];
  const float* bk   = (const float*)d_in[4];
  const float* Wv   = (const float*)d_in[5];
  const float* bv   = (const float*)d_in[6];
  const float* Wo   = (const float*)d_in[7];
  const float* bo   = (const float*)d_in[8];
  const float* ln1w = (const float*)d_in[9];
  const float* ln1b = (const float*)d_in[10];
  const float* W1   = (const float*)d_in[11];
  const float* b1   = (const float*)d_in[12];
  const float* W2   = (const float*)d_in[13];
  const float* b2   = (const float*)d_in[14];
  const float* ln2w = (const float*)d_in[15];
  const float* ln2b = (const float*)d_in[16];
  float* out = (float*)d_out;

  char* ws = (char*)d_ws;
  size_t off = 0;
  auto alloc = [&](size_t bytes) {
    char* p = ws + off;
    off += (bytes + 255) & ~(size_t)255;
    return p;
  };
  unsigned short* WTqkv = (unsigned short*)alloc(1536 * 512 * 2);
  unsigned short* WoT   = (unsigned short*)alloc(512 * 512 * 2);
  unsigned short* W1T   = (unsigned short*)alloc(2048 * 512 * 2);
  unsigned short* W2T   = (unsigned short*)alloc(512 * 2048 * 2);
  float*          biasqkv = (float*)alloc(1536 * 4);
  unsigned short* zb    = (unsigned short*)alloc((size_t)8192 * 512 * 2);
  unsigned short* qkvb  = (unsigned short*)alloc((size_t)8192 * 1536 * 2);
  unsigned short* attnb = (unsigned short*)alloc((size_t)8192 * 512 * 2);
  float*          proj  = (float*)alloc((size_t)8192 * 512 * 4);
  float*          z1    = (float*)alloc((size_t)8192 * 512 * 4);
  unsigned short* z1b   = zb;    // reuse (zb dead after QKV GEMM)
  unsigned short* ff    = qkvb;  // reuse qkvb+attnb (contiguous 33.5MB; dead after Wo GEMM)

  dim3 tb(32, 8);
  k_f32_to_bf16<<<4096, 256, 0, stream>>>(z, zb, 1048576);
  k_transpose_bf16<<<dim3(16, 16), tb, 0, stream>>>(Wq, WTqkv, 512, 512);
  k_transpose_bf16<<<dim3(16, 16), tb, 0, stream>>>(Wk, WTqkv + 512 * 512, 512, 512);
  k_transpose_bf16<<<dim3(16, 16), tb, 0, stream>>>(Wv, WTqkv + 1024 * 512, 512, 512);
  k_transpose_bf16<<<dim3(16, 16), tb, 0, stream>>>(Wo, WoT, 512, 512);
  k_transpose_bf16<<<dim3(64, 16), tb, 0, stream>>>(W1, W1T, 512, 2048);
  k_transpose_bf16<<<dim3(16, 64), tb, 0, stream>>>(W2, W2T, 2048, 512);
  k_concat_bias<<<6, 256, 0, stream>>>(bq, bk, bv, biasqkv);

  // QKV: [8192,512] @ [512,1536] -> qkvb
  k_gemm<0><<<dim3(12, 64), 256, 0, stream>>>(zb, WTqkv, biasqkv, qkvb, 512, 1536);
  // windowed attention
  k_attn<<<1024, 64, 0, stream>>>(qkvb, attnb);
  // Wo proj: [8192,512] @ [512,512] -> proj (f32)
  k_gemm<1><<<dim3(4, 64), 256, 0, stream>>>(attnb, WoT, bo, proj, 512, 512);
  // z1 = LN(z + proj)
  k_ln<<<2048, 256, 0, stream>>>(z, proj, ln1w, ln1b, z1, z1b);
  // FFN1: [8192,512] @ [512,2048] + GELU -> ff (bf16)
  k_gemm<2><<<dim3(16, 64), 256, 0, stream>>>(z1b, W1T, b1, ff, 512, 2048);
  // FFN2: [8192,2048] @ [2048,512] -> proj (f32)
  k_gemm<1><<<dim3(4, 64), 256, 0, stream>>>(ff, W2T, b2, proj, 2048, 512);
  // out = LN(z1 + proj)
  k_ln<<<2048, 256, 0, stream>>>(z1, proj, ln2w, ln2b, out, nullptr);
}

// Round 3
// 172.112 us; speedup vs baseline: 1.1427x; 1.0087x over previous
//
#include <hip/hip_runtime.h>
#include <cstdint>
#include <cstddef>

#define DEV __device__ __forceinline__

typedef __bf16 bf16x8 __attribute__((ext_vector_type(8)));
typedef float f32x4 __attribute__((ext_vector_type(4)));
typedef unsigned short us8 __attribute__((ext_vector_type(8)));
typedef unsigned short us4 __attribute__((ext_vector_type(4)));

typedef const __attribute__((address_space(1))) unsigned int GUI;
typedef __attribute__((address_space(3))) unsigned int LUI;

DEV unsigned short f2bf(float f) {
  unsigned int u = __builtin_bit_cast(unsigned int, f);
  u += 0x7fffu + ((u >> 16) & 1u);
  return (unsigned short)(u >> 16);
}
DEV float bf2f(unsigned short h) {
  unsigned int u = ((unsigned int)h) << 16;
  return __builtin_bit_cast(float, u);
}

// ---------------- convert f32 -> bf16 (vectorized) ----------------
__global__ void k_f32_to_bf16(const float* __restrict__ in, unsigned short* __restrict__ out, int n4) {
  int i = blockIdx.x * blockDim.x + threadIdx.x;
  if (i >= n4) return;
  float4 v = ((const float4*)in)[i];
  us4 o;
  o.x = f2bf(v.x); o.y = f2bf(v.y); o.z = f2bf(v.z); o.w = f2bf(v.w);
  *(us4*)(out + (size_t)i * 4) = o;
}

// ------------- transpose [K,N] f32 -> [N,K] bf16 ------------------
__global__ void k_transpose_bf16(const float* __restrict__ in, unsigned short* __restrict__ out,
                                 int K, int N) {
  __shared__ float tile[32][33];
  int n0 = blockIdx.x * 32, k0 = blockIdx.y * 32;
  int tx = threadIdx.x, ty = threadIdx.y;  // block (32,8)
#pragma unroll
  for (int i = 0; i < 32; i += 8)
    tile[ty + i][tx] = in[(size_t)(k0 + ty + i) * N + n0 + tx];
  __syncthreads();
#pragma unroll
  for (int i = 0; i < 32; i += 8)
    out[(size_t)(n0 + ty + i) * K + k0 + tx] = f2bf(tile[tx][ty + i]);
}

// --------- fused transpose of four 512x512 f32 -> bf16 [N,K] ------
__global__ void k_transpose4(const float* __restrict__ p0, const float* __restrict__ p1,
                             const float* __restrict__ p2, const float* __restrict__ p3,
                             unsigned short* __restrict__ base) {
  __shared__ float tile[32][33];
  const float* in = blockIdx.z == 0 ? p0 : blockIdx.z == 1 ? p1 : blockIdx.z == 2 ? p2 : p3;
  unsigned short* out = base + (size_t)blockIdx.z * 262144;
  int n0 = blockIdx.x * 32, k0 = blockIdx.y * 32;
  int tx = threadIdx.x, ty = threadIdx.y;  // block (32,8)
#pragma unroll
  for (int i = 0; i < 32; i += 8)
    tile[ty + i][tx] = in[(size_t)(k0 + ty + i) * 512 + n0 + tx];
  __syncthreads();
#pragma unroll
  for (int i = 0; i < 32; i += 8)
    out[(size_t)(n0 + ty + i) * 512 + k0 + tx] = f2bf(tile[tx][ty + i]);
}

// ---------------- concat q/k/v biases -----------------------------
__global__ void k_concat_bias(const float* __restrict__ bq, const float* __restrict__ bk,
                              const float* __restrict__ bv, float* __restrict__ out) {
  int i = blockIdx.x * blockDim.x + threadIdx.x;  // 1536
  float v = (i < 512) ? bq[i] : (i < 1024 ? bk[i - 512] : bv[i - 1024]);
  out[i] = v;
}

// ---------------- bf16 MFMA GEMM: C = A @ BT^T + bias -------------
// A: [M,K] bf16 row-major, BT: [N,K] bf16 row-major.
// MODE 0: bf16 out; MODE 1: f32 out; MODE 2: bf16 out + exact GELU.
// SPLITK: gridDim.z parts; z==0 -> outp (+bias), z==1 -> outp2 (no bias).
// Pipeline: depth-2 prefetch via global_load_lds, 3 LDS buffers, counted
// vmcnt waits (never 0 mid-loop), raw s_barrier. LDS chunk-XOR swizzle
// (both-sides involution, applied on the per-lane global source address).
template <int MODE, int SPLITK>
__global__ __launch_bounds__(256) void k_gemm(const unsigned short* __restrict__ A,
                                              const unsigned short* __restrict__ BT,
                                              const float* __restrict__ bias,
                                              void* __restrict__ outp, void* __restrict__ outp2,
                                              int K, int N) {
  __shared__ __align__(16) unsigned short As[3 * 4096];
  __shared__ __align__(16) unsigned short Bs[3 * 4096];
  const int tid = threadIdx.x;
  const int wave = tid >> 6, lane = tid & 63;
  const int wm = wave >> 1, wn = wave & 1;
  const int rbase = blockIdx.y * 128;
  const int nbase = blockIdx.x * 128;
  const int z = (SPLITK > 1) ? blockIdx.z : 0;
  const int nkt = (K / SPLITK) >> 5;
  const int ktb = z * nkt;

  // Preload bias and DRAIN before the pipeline: the loop's vmcnt counting
  // assumes only the staged global_load_lds ops are outstanding.
  float bv_[4];
#pragma unroll
  for (int n = 0; n < 4; ++n) {
    int gcol = nbase + wn * 64 + n * 16 + (lane & 15);
    bv_[n] = (z == 0) ? bias[gcol] : 0.f;
  }
  asm volatile("s_waitcnt vmcnt(0)" ::: "memory");

  auto STAGE = [&](int buf, int kt) {
    const int k0 = kt << 5;
#pragma unroll
    for (int t = 0; t < 2; ++t) {
      int s = (wave + t * 4) * 64 + lane;                  // slot in [0,512)
      int row = s >> 2;
      int col = ((s & 3) ^ ((s >> 3) & 3)) << 3;           // swizzled source chunk
      const unsigned short* ga = A + (size_t)(rbase + row) * K + k0 + col;
      const unsigned short* gb = BT + (size_t)(nbase + row) * K + k0 + col;
      __builtin_amdgcn_global_load_lds((GUI*)ga, (LUI*)(As + buf * 4096 + (wave + t * 4) * 512), 16, 0, 0);
      __builtin_amdgcn_global_load_lds((GUI*)gb, (LUI*)(Bs + buf * 4096 + (wave + t * 4) * 512), 16, 0, 0);
    }
  };

  f32x4 acc[4][4] = {};
  STAGE(0, ktb);
  STAGE(1, ktb + 1);

  for (int kt = 0; kt < nkt; ++kt) {
    const int cur = kt % 3;
    if (kt + 2 < nkt) {
      STAGE((kt + 2) % 3, ktb + kt + 2);
      asm volatile("s_waitcnt vmcnt(8)" ::: "memory");
    } else if (kt + 1 < nkt) {
      asm volatile("s_waitcnt vmcnt(4)" ::: "memory");
    } else {
      asm volatile("s_waitcnt vmcnt(0)" ::: "memory");
    }
    __builtin_amdgcn_s_barrier();  // tile `cur` fully in LDS (all waves)

    bf16x8 af[4], bfr[4];
#pragma unroll
    for (int m = 0; m < 4; ++m) {
      int row = wm * 64 + m * 16 + (lane & 15);
      int qs = (lane >> 4) ^ ((row >> 1) & 3);
      af[m] = __builtin_bit_cast(bf16x8, *(const us8*)(As + cur * 4096 + row * 32 + qs * 8));
    }
#pragma unroll
    for (int n = 0; n < 4; ++n) {
      int row = wn * 64 + n * 16 + (lane & 15);
      int qs = (lane >> 4) ^ ((row >> 1) & 3);
      bfr[n] = __builtin_bit_cast(bf16x8, *(const us8*)(Bs + cur * 4096 + row * 32 + qs * 8));
    }
#pragma unroll
    for (int m = 0; m < 4; ++m)
#pragma unroll
      for (int n = 0; n < 4; ++n)
        acc[m][n] = __builtin_amdgcn_mfma_f32_16x16x32_bf16(af[m], bfr[n], acc[m][n], 0, 0, 0);
    asm volatile("s_waitcnt lgkmcnt(0)" ::: "memory");
    __builtin_amdgcn_s_barrier();  // tile `cur` consumed; its buffer may be restaged
  }

  void* opv = (z == 0) ? outp : outp2;
#pragma unroll
  for (int m = 0; m < 4; ++m) {
    int grow0 = rbase + wm * 64 + m * 16 + ((lane >> 4) << 2);
#pragma unroll
    for (int n = 0; n < 4; ++n) {
      int gcol = nbase + wn * 64 + n * 16 + (lane & 15);
#pragma unroll
      for (int r = 0; r < 4; ++r) {
        float v = acc[m][n][r] + bv_[n];
        if (MODE == 2) v = 0.5f * v * (1.0f + erff(v * 0.70710678118654752f));
        if (MODE == 1)
          ((float*)opv)[(size_t)(grow0 + r) * N + gcol] = v;
        else
          ((unsigned short*)opv)[(size_t)(grow0 + r) * N + gcol] = f2bf(v);
      }
    }
  }
}

// ---------------- windowed causal attention (v2) ------------------
__global__ __launch_bounds__(64) void k_attn(const unsigned short* __restrict__ qkv,
                                             unsigned short* __restrict__ attnb) {
  __shared__ float Qt[64 * 67];  // [d][q]
  __shared__ float Kt[64 * 75];  // [d][t]
  __shared__ float P[64 * 12];   // [q][jj]

  const int lane = threadIdx.x;
  const int bid = blockIdx.x;          // 1024 = 32 chunks x 32 bh
  const int chunk = bid & 31;
  const int bh = bid >> 5;
  const int h = bh & 7, b = bh >> 3;
  const int i0 = chunk * 64;
  const int b2048 = b * 2048;
  const int h64 = h * 64;

#pragma unroll 8
  for (int r = 0; r < 73; ++r) {
    int jloc = i0 - 9 + r;
    int jc = jloc < 0 ? 0 : jloc;
    Kt[lane * 75 + r] = bf2f(qkv[(size_t)(b2048 + jc) * 1536 + 512 + h64 + lane]);
  }
#pragma unroll 8
  for (int r = 0; r < 64; ++r) {
    Qt[lane * 67 + r] = bf2f(qkv[(size_t)(b2048 + i0 + r) * 1536 + h64 + lane]);
  }
  __syncthreads();

  float s[10];
#pragma unroll
  for (int jj = 0; jj < 10; ++jj) s[jj] = 0.f;
#pragma unroll
  for (int d = 0; d < 64; ++d) {
    float qd = Qt[d * 67 + lane];
#pragma unroll
    for (int jj = 0; jj < 10; ++jj)
      s[jj] = fmaf(qd, Kt[d * 75 + lane + jj], s[jj]);
  }
  const int iG = i0 + lane;
#pragma unroll
  for (int jj = 0; jj < 10; ++jj)
    s[jj] = (iG - 9 + jj >= 0) ? s[jj] * 0.125f : -1e30f;
  float mx = s[9];
#pragma unroll
  for (int jj = 0; jj < 9; ++jj) mx = fmaxf(mx, s[jj]);
  float den = 0.f;
#pragma unroll
  for (int jj = 0; jj < 10; ++jj) {
    s[jj] = __expf(s[jj] - mx);
    den += s[jj];
  }
  float inv = 1.f / den;
#pragma unroll
  for (int jj = 0; jj < 10; ++jj) P[lane * 12 + jj] = s[jj] * inv;
  __syncthreads();

  for (int q0 = 0; q0 < 64; q0 += 4) {
    float vv[13];
#pragma unroll
    for (int t = 0; t < 13; ++t) {
      int jloc = i0 + q0 - 9 + t;
      int jc = jloc < 0 ? 0 : jloc;
      vv[t] = bf2f(qkv[(size_t)(b2048 + jc) * 1536 + 1024 + h64 + lane]);
    }
#pragma unroll
    for (int qq = 0; qq < 4; ++qq) {
      const int q = q0 + qq;
      const float* pp = &P[q * 12];
      float o = 0.f;
#pragma unroll
      for (int jj = 0; jj < 10; ++jj) o = fmaf(pp[jj], vv[qq + jj], o);
      attnb[(size_t)(b2048 + i0 + q) * 512 + h64 + lane] = f2bf(o);
    }
  }
}

// ---------------- residual + LayerNorm ----------------------------
// y = LN(res + add [+ add2]); writes f32 (and optionally bf16 copy)
__global__ __launch_bounds__(256) void k_ln(const float* __restrict__ res,
                                            const float* __restrict__ add,
                                            const float* __restrict__ add2,
                                            const float* __restrict__ w,
                                            const float* __restrict__ bb,
                                            float* __restrict__ out_f32,
                                            unsigned short* __restrict__ out_bf16) {
  const int wave = threadIdx.x >> 6, lane = threadIdx.x & 63;
  const int row = blockIdx.x * 4 + wave;
  const float4* r4 = (const float4*)(res + (size_t)row * 512);
  const float4* a4 = (const float4*)(add + (size_t)row * 512);
  const float4* a24 = (const float4*)(add2 + (size_t)row * 512);
  float4 x[2];
  float sum = 0.f, ss = 0.f;
#pragma unroll
  for (int t = 0; t < 2; ++t) {
    float4 rv = r4[lane * 2 + t], av = a4[lane * 2 + t];
    float4 y;
    y.x = rv.x + av.x; y.y = rv.y + av.y; y.z = rv.z + av.z; y.w = rv.w + av.w;
    if (add2) {
      float4 a2 = a24[lane * 2 + t];
      y.x += a2.x; y.y += a2.y; y.z += a2.z; y.w += a2.w;
    }
    x[t] = y;
    sum += y.x + y.y + y.z + y.w;
    ss += y.x * y.x + y.y * y.y + y.z * y.z + y.w * y.w;
  }
#pragma unroll
  for (int m = 32; m >= 1; m >>= 1) {
    sum += __shfl_xor(sum, m);
    ss += __shfl_xor(ss, m);
  }
  const float mu = sum * (1.f / 512.f);
  float var = ss * (1.f / 512.f) - mu * mu;
  const float rstd = rsqrtf(var + 1e-5f);
#pragma unroll
  for (int t = 0; t < 2; ++t) {
    int c = lane * 8 + t * 4;
    float4 wv = *(const float4*)(w + c);
    float4 bv = *(const float4*)(bb + c);
    float4 y = x[t];
    float4 o;
    o.x = (y.x - mu) * rstd * wv.x + bv.x;
    o.y = (y.y - mu) * rstd * wv.y + bv.y;
    o.z = (y.z - mu) * rstd * wv.z + bv.z;
    o.w = (y.w - mu) * rstd * wv.w + bv.w;
    if (out_f32) *(float4*)(out_f32 + (size_t)row * 512 + c) = o;
    if (out_bf16) {
      us4 u;
      u.x = f2bf(o.x); u.y = f2bf(o.y); u.z = f2bf(o.z); u.w = f2bf(o.w);
      *(us4*)(out_bf16 + (size_t)row * 512 + c) = u;
    }
  }
}

extern "C" void kernel_launch(void* const* d_in, const int* in_sizes, int n_in,
                              void* d_out, int out_size, void* d_ws, size_t ws_size,
                              hipStream_t stream) {
  const float* z    = (const float*)d_in[0];
  const float* Wq   = (const float*)d_in[1];
  const float* bq   = (const float*)d_in[2];
  const float* Wk   = (const float*)d_in[3];
  const float* bk   = (const float*)d_in[4];
  const float* Wv   = (const float*)d_in[5];
  const float* bv   = (const float*)d_in[6];
  const float* Wo   = (const float*)d_in[7];
  const float* bo   = (const float*)d_in[8];
  const float* ln1w = (const float*)d_in[9];
  const float* ln1b = (const float*)d_in[10];
  const float* W1   = (const float*)d_in[11];
  const float* b1   = (const float*)d_in[12];
  const float* W2   = (const float*)d_in[13];
  const float* b2   = (const float*)d_in[14];
  const float* ln2w = (const float*)d_in[15];
  const float* ln2b = (const float*)d_in[16];
  float* out = (float*)d_out;

  char* ws = (char*)d_ws;
  size_t off = 0;
  auto alloc = [&](size_t bytes) {
    char* p = ws + off;
    off += (bytes + 255) & ~(size_t)255;
    return p;
  };
  unsigned short* Wsq   = (unsigned short*)alloc((size_t)2048 * 512 * 2);  // WqT|WkT|WvT|WoT
  unsigned short* WTqkv = Wsq;
  unsigned short* WoT   = Wsq + (size_t)1536 * 512;
  unsigned short* W1T   = (unsigned short*)alloc((size_t)2048 * 512 * 2);
  unsigned short* W2T   = (unsigned short*)alloc((size_t)512 * 2048 * 2);
  float*          biasqkv = (float*)alloc(1536 * 4);
  unsigned short* zb    = (unsigned short*)alloc((size_t)8192 * 512 * 2);
  unsigned short* qkvb  = (unsigned short*)alloc((size_t)8192 * 1536 * 2);
  unsigned short* attnb = (unsigned short*)alloc((size_t)8192 * 512 * 2);
  float*          proj  = (float*)alloc((size_t)8192 * 512 * 4);
  float*          z1    = (float*)alloc((size_t)8192 * 512 * 4);
  unsigned short* z1b   = zb;    // reuse (zb dead after QKV GEMM)
  unsigned short* ff    = qkvb;  // reuse qkvb+attnb (dead after Wo GEMM)

  dim3 tb(32, 8);
  k_f32_to_bf16<<<4096, 256, 0, stream>>>(z, zb, 1048576);
  k_transpose4<<<dim3(16, 16, 4), tb, 0, stream>>>(Wq, Wk, Wv, Wo, Wsq);
  k_transpose_bf16<<<dim3(64, 16), tb, 0, stream>>>(W1, W1T, 512, 2048);
  k_transpose_bf16<<<dim3(16, 64), tb, 0, stream>>>(W2, W2T, 2048, 512);
  k_concat_bias<<<6, 256, 0, stream>>>(bq, bk, bv, biasqkv);

  // QKV: [8192,512] @ [512,1536] -> qkvb (bf16)
  k_gemm<0, 1><<<dim3(12, 64), 256, 0, stream>>>(zb, WTqkv, biasqkv, qkvb, nullptr, 512, 1536);
  // windowed attention
  k_attn<<<1024, 64, 0, stream>>>(qkvb, attnb);
  // Wo proj: [8192,512] @ [512,512] -> proj (f32)
  k_gemm<1, 1><<<dim3(4, 64), 256, 0, stream>>>(attnb, WoT, bo, proj, nullptr, 512, 512);
  // z1 = LN(z + proj)
  k_ln<<<2048, 256, 0, stream>>>(z, proj, nullptr, ln1w, ln1b, z1, z1b);
  // FFN1: [8192,512] @ [512,2048] + GELU -> ff (bf16)
  k_gemm<2, 1><<<dim3(16, 64), 256, 0, stream>>>(z1b, W1T, b1, ff, nullptr, 512, 2048);
  // FFN2: [8192,2048] @ [2048,512] split-K=2 -> proj (z=0, +bias) and d_out (z=1)
  k_gemm<1, 2><<<dim3(4, 64, 2), 256, 0, stream>>>(ff, W2T, b2, proj, out, 2048, 512);
  // out = LN(z1 + proj + out_partial)
  k_ln<<<2048, 256, 0, stream>>>(z1, proj, out, ln2w, ln2b, out, nullptr);
}